// Round 4
// baseline (775.481 us; speedup 1.0000x reference)
//
#include <hip/hip_runtime.h>
#include <hip/hip_bf16.h>

typedef __attribute__((ext_vector_type(8))) short short8_t;
typedef __attribute__((ext_vector_type(4))) float f32x4;

#define DEV __device__ __forceinline__

constexpr int BB = 8;           // batch
constexpr int NV = 10242;       // vertices
constexpr int NE = 61440;       // edges
constexpr int MROWS = BB * NV;  // 81936
constexpr int KD = 512;         // K for layers 1-5

DEV float bf2f(ushort u) { union { unsigned i; float f; } v; v.i = ((unsigned)u) << 16; return v.f; }
DEV ushort f2bf(float f) {
    union { unsigned i; float f; } v; v.f = f;
    unsigned b = v.i;
    b += 0x7fffu + ((b >> 16) & 1u);   // RNE
    return (ushort)(b >> 16);
}

// ---------------- CSR build ----------------
__global__ void k_init(int* deg, int* fill) {
    int i = blockIdx.x * 256 + threadIdx.x;
    if (i < NV) { deg[i] = 1; fill[i] = 0; }   // self-loop counts as 1
}

__global__ void k_count(const int* __restrict__ ei, int* __restrict__ deg) {
    int e = blockIdx.x * 256 + threadIdx.x;
    if (e < NE) atomicAdd(&deg[ei[NE + e]], 1);   // dst row of edge_indices
}

__global__ void k_dinv(const int* __restrict__ deg, float* __restrict__ dinv) {
    int i = blockIdx.x * 256 + threadIdx.x;
    if (i < NV) dinv[i] = rsqrtf((float)deg[i]);
}

__global__ __launch_bounds__(1024) void k_scan(const int* __restrict__ cnt, int* __restrict__ rp) {
    __shared__ int part[1024];
    const int t = threadIdx.x;
    const int chunk = (NV + 1023) / 1024;   // 11
    int b0 = t * chunk, b1 = min(b0 + chunk, NV);
    int s = 0;
    for (int i = b0; i < b1; ++i) s += cnt[i];
    part[t] = s;
    __syncthreads();
    for (int off = 1; off < 1024; off <<= 1) {
        int v = (t >= off) ? part[t - off] : 0;
        __syncthreads();
        part[t] += v;
        __syncthreads();
    }
    int run = (t == 0) ? 0 : part[t - 1];
    for (int i = b0; i < b1; ++i) { rp[i] = run; run += cnt[i]; }
    if (t == 1023) rp[NV] = part[1023];
}

__global__ void k_fill(const int* __restrict__ ei, const int* __restrict__ rp,
                       int* __restrict__ fill, const float* __restrict__ dinv,
                       int* __restrict__ ci, float* __restrict__ val) {
    int e = blockIdx.x * 256 + threadIdx.x;
    if (e >= NE + NV) return;
    int s, d;
    if (e < NE) { s = ei[e]; d = ei[NE + e]; }
    else        { s = d = e - NE; }           // self-loops
    int p = atomicAdd(&fill[d], 1);
    int pos = rp[d] + p;
    ci[pos] = s;
    val[pos] = dinv[s] * dinv[d];
}

// ---------------- weight convert / transpose:  Wt[n][k] = bf16(W[k][n]) ----------------
__global__ void k_wconv(const float* __restrict__ W, ushort* __restrict__ Wt, int Kd, int Nc) {
    int idx = blockIdx.x * 256 + threadIdx.x;
    if (idx >= Kd * Nc) return;
    int n = idx / Kd, k = idx - n * Kd;
    Wt[idx] = f2bf(W[(size_t)k * Nc + n]);
}

// ---------------- layer 1 ----------------
// base[b][c] = sum_k img[b][k] * W1[3+k][c]
__global__ __launch_bounds__(128) void k_l1base(const float* __restrict__ img, const float* __restrict__ W1,
                                                float* __restrict__ base) {
    int c = blockIdx.x * 128 + threadIdx.x;   // grid.x = 4
    int b = blockIdx.y;
    float s = 0.f;
    for (int k = 0; k < 512; ++k) s = fmaf(img[b * 512 + k], W1[(size_t)(3 + k) * 512 + c], s);
    base[b * 512 + c] = s;
}

// h[row(i,b), c], vertex-major: row = i*BB + b. 2 rows per 256-thread block.
__global__ __launch_bounds__(256) void k_l1h(const float* __restrict__ verts, const float* __restrict__ W1,
                                             const float* __restrict__ base, ushort* __restrict__ h) {
    const int t = threadIdx.x;
    int row = blockIdx.x * 2 + (t >> 7);       // activation row = i*BB + b
    if (row >= MROWS) return;
    int i = row >> 3, b = row & 7;
    size_t vrow = (size_t)b * NV + i;          // input order [B][N][3]
    float v0 = verts[vrow * 3 + 0], v1 = verts[vrow * 3 + 1], v2 = verts[vrow * 3 + 2];
    int c = (t & 127) * 4;
    float4 w0 = *(const float4*)&W1[c];
    float4 w1 = *(const float4*)&W1[512 + c];
    float4 w2 = *(const float4*)&W1[1024 + c];
    float4 bs = *(const float4*)&base[b * 512 + c];
    ushort4 o;
    o.x = f2bf(v0 * w0.x + v1 * w1.x + v2 * w2.x + bs.x);
    o.y = f2bf(v0 * w0.y + v1 * w1.y + v2 * w2.y + bs.y);
    o.z = f2bf(v0 * w0.z + v1 * w1.z + v2 * w2.z + bs.z);
    o.w = f2bf(v0 * w0.w + v1 * w1.w + v2 * w2.w + bs.w);
    *(ushort4*)&h[(size_t)row * 512 + c] = o;
}

// ---------------- GEMM: C[M,Nc] = A[M,512] @ Wt[Nc,512]^T  (bf16 in, bf16 out, f32 acc) ----------------
// 1-D grid, XCD row-affinity: all column-blocks of a row-chunk land on the same XCD
// (bid%8 round-robin heuristic) so the A-chunk is read from HBM once per XCD.
__global__ __launch_bounds__(256) void k_gemm(const ushort* __restrict__ A, const ushort* __restrict__ Bt,
                                              ushort* __restrict__ C, int Mr, int Nc) {
    const int ncb = (Nc + 127) >> 7;           // column blocks
    const int nrc = (Mr + 127) >> 7;           // row chunks
    const int cpx = (nrc + 7) >> 3;            // row chunks per XCD (ceil)
    const int bid = blockIdx.x;
    const int xcd = bid & 7;
    const int k = bid >> 3;                    // 0 .. cpx*ncb-1
    const int rc = xcd * cpx + k / ncb;
    const int cb = k % ncb;
    if (rc >= nrc) return;

    __shared__ __align__(16) ushort lA[2][4096];   // [128 rows][32 k]
    __shared__ __align__(16) ushort lB[2][4096];   // [128 cols][32 k]
    const int t = threadIdx.x;
    const int lane = t & 63, w = t >> 6;
    const int wr = w >> 1, wc = w & 1;
    const int r0 = rc * 128, c0 = cb * 128;

    const ushort* gA[2]; const ushort* gB[2];
    int ldsoff[2];
    #pragma unroll
    for (int i2 = 0; i2 < 2; ++i2) {
        int idx = i2 * 256 + t;
        int row = idx >> 2, slot = idx & 3;
        int ar = min(r0 + row, Mr - 1);
        int bc = min(c0 + row, Nc - 1);
        gA[i2] = A + (size_t)ar * KD + slot * 8;
        gB[i2] = Bt + (size_t)bc * KD + slot * 8;
        ldsoff[i2] = i2 * 2048 + w * 512;   // elements; wave-uniform
    }

    auto stage = [&](int buf, int kt) {
        int ko = kt * 32;
        #pragma unroll
        for (int i2 = 0; i2 < 2; ++i2) {
            __builtin_amdgcn_global_load_lds(
                (const __attribute__((address_space(1))) void*)(gA[i2] + ko),
                (__attribute__((address_space(3))) void*)(&lA[buf][ldsoff[i2]]), 16, 0, 0);
            __builtin_amdgcn_global_load_lds(
                (const __attribute__((address_space(1))) void*)(gB[i2] + ko),
                (__attribute__((address_space(3))) void*)(&lB[buf][ldsoff[i2]]), 16, 0, 0);
        }
    };

    f32x4 acc[4][4] = {};
    stage(0, 0);
    __syncthreads();
    int cur = 0;
    const int kslot = (lane >> 4) * 8;
    const int rloc = lane & 15;
    for (int kt = 0; kt < 16; ++kt) {
        if (kt < 15) stage(cur ^ 1, kt + 1);
        short8_t af[4], bfr[4];
        #pragma unroll
        for (int m = 0; m < 4; ++m) {
            af[m]  = *(const short8_t*)&lA[cur][(wr * 64 + m * 16 + rloc) * 32 + kslot];
            bfr[m] = *(const short8_t*)&lB[cur][(wc * 64 + m * 16 + rloc) * 32 + kslot];
        }
        #pragma unroll
        for (int m = 0; m < 4; ++m)
            #pragma unroll
            for (int n = 0; n < 4; ++n)
                acc[m][n] = __builtin_amdgcn_mfma_f32_16x16x32_bf16(af[m], bfr[n], acc[m][n], 0, 0, 0);
        __syncthreads();
        cur ^= 1;
    }

    const int orow = r0 + wr * 64 + (lane >> 4) * 4;
    const int ocol = c0 + wc * 64 + rloc;
    #pragma unroll
    for (int m = 0; m < 4; ++m) {
        #pragma unroll
        for (int n = 0; n < 4; ++n) {
            int gc = ocol + n * 16;
            if (gc >= Nc) continue;
            #pragma unroll
            for (int r = 0; r < 4; ++r) {
                int gr = orow + m * 16 + r;
                if (gr < Mr) C[(size_t)gr * Nc + gc] = f2bf(acc[m][n][r]);
            }
        }
    }
}

// ---------------- vertex-major batch-fused aggregation ----------------
// One block per vertex; aggregates all 8 batches. Per edge the block reads one
// contiguous 8*F bf16 chunk; thread t owns 16B of it. Edges processed in
// zero-weight-padded groups of 4 -> 4 independent 16B loads in flight/thread.
// Output stored NON-TEMPORAL: the 84MB write stream must not evict h from LLC
// (h is re-read deg~7x at random times; R3 FETCH=3.3x h says LLC was thrashing).
template <int F, int NT, bool RELU>
__global__ __launch_bounds__(NT) void k_aggv(const ushort* __restrict__ h, ushort* __restrict__ xo,
                                             const int* __restrict__ rp, const int* __restrict__ ci,
                                             const float* __restrict__ val, const float* __restrict__ bias) {
    constexpr int CH = BB * F;                // chunk elements (4096 / 512)
    static_assert(NT * 8 == CH, "one short8 per thread");
    const int i = blockIdx.x;
    const int t = threadIdx.x;
    const int r0 = rp[i], r1 = rp[i + 1];
    const ushort* hb = h + t * 8;
    float acc[8] = {};
    for (int e = r0; e < r1; e += 4) {
        const bool p1 = e + 1 < r1, p2 = e + 2 < r1, p3 = e + 3 < r1;
        const int j0 = ci[e];
        const int j1 = p1 ? ci[e + 1] : j0;
        const int j2 = p2 ? ci[e + 2] : j0;
        const int j3 = p3 ? ci[e + 3] : j0;
        const float w0 = val[e];
        const float w1 = p1 ? val[e + 1] : 0.f;
        const float w2 = p2 ? val[e + 2] : 0.f;
        const float w3 = p3 ? val[e + 3] : 0.f;
        const short8_t v0 = *(const short8_t*)(hb + (size_t)j0 * CH);
        const short8_t v1 = *(const short8_t*)(hb + (size_t)j1 * CH);
        const short8_t v2 = *(const short8_t*)(hb + (size_t)j2 * CH);
        const short8_t v3 = *(const short8_t*)(hb + (size_t)j3 * CH);
        #pragma unroll
        for (int k = 0; k < 8; ++k) {
            float a = acc[k];
            a = fmaf(w0, bf2f((ushort)v0[k]), a);
            a = fmaf(w1, bf2f((ushort)v1[k]), a);
            a = fmaf(w2, bf2f((ushort)v2[k]), a);
            a = fmaf(w3, bf2f((ushort)v3[k]), a);
            acc[k] = a;
        }
    }
    const int fb = (t * 8) & (F - 1);
    const float4 bl = *(const float4*)&bias[fb];
    const float4 bh = *(const float4*)&bias[fb + 4];
    const float bb[8] = {bl.x, bl.y, bl.z, bl.w, bh.x, bh.y, bh.z, bh.w};
    short8_t o;
    #pragma unroll
    for (int k = 0; k < 8; ++k) {
        float a = acc[k] + bb[k];
        if (RELU) a = fmaxf(a, 0.f);
        o[k] = (short)f2bf(a);
    }
    __builtin_nontemporal_store(o, (short8_t*)(xo + (size_t)i * CH + t * 8));
}

// ---------------- layer 6: h3 = x64 @ W6 (64x3, f32), rows vertex-major ----------------
__global__ __launch_bounds__(256) void k_l6(const ushort* __restrict__ x64, const float* __restrict__ W6,
                                            float* __restrict__ h3) {
    __shared__ float w[192];
    if (threadIdx.x < 192) w[threadIdx.x] = W6[threadIdx.x];
    __syncthreads();
    int r = blockIdx.x * 256 + threadIdx.x;
    if (r >= MROWS) return;
    const ushort* xr = x64 + (size_t)r * 64;
    float a0 = 0, a1 = 0, a2 = 0;
    #pragma unroll 8
    for (int k = 0; k < 64; ++k) {
        float xv = bf2f(xr[k]);
        a0 = fmaf(xv, w[k * 3 + 0], a0);
        a1 = fmaf(xv, w[k * 3 + 1], a1);
        a2 = fmaf(xv, w[k * 3 + 2], a2);
    }
    float* o = h3 + (size_t)r * 3;
    o[0] = a0; o[1] = a1; o[2] = a2;
}

// final aggregation: h3 vertex-major [i*8+b][3] -> out [b][i][3]
__global__ __launch_bounds__(256) void k_agg3(const float* __restrict__ h3, float* __restrict__ out,
                                              const int* __restrict__ rp, const int* __restrict__ ci,
                                              const float* __restrict__ val, const float* __restrict__ b6) {
    int idx = blockIdx.x * 256 + threadIdx.x;
    if (idx >= MROWS) return;
    int b = idx / NV, i = idx - b * NV;
    float a0 = b6[0], a1 = b6[1], a2 = b6[2];
    int r0 = rp[i], r1 = rp[i + 1];
    for (int e = r0; e < r1; ++e) {
        int j = ci[e];
        float wv = val[e];
        const float* hr = h3 + ((size_t)j * BB + b) * 3;
        a0 = fmaf(wv, hr[0], a0);
        a1 = fmaf(wv, hr[1], a1);
        a2 = fmaf(wv, hr[2], a2);
    }
    float* o = out + (size_t)idx * 3;
    o[0] = a0; o[1] = a1; o[2] = a2;
}

// ---------------- launcher ----------------
extern "C" void kernel_launch(void* const* d_in, const int* in_sizes, int n_in,
                              void* d_out, int out_size, void* d_ws, size_t ws_size,
                              hipStream_t stream) {
    const float* verts = (const float*)d_in[0];
    const float* img   = (const float*)d_in[1];
    const int*   ei    = (const int*)d_in[2];
    const float* W1 = (const float*)d_in[3];  const float* b1 = (const float*)d_in[4];
    const float* W2 = (const float*)d_in[5];  const float* b2 = (const float*)d_in[6];
    const float* W3 = (const float*)d_in[7];  const float* b3 = (const float*)d_in[8];
    const float* W4 = (const float*)d_in[9];  const float* b4 = (const float*)d_in[10];
    const float* W5 = (const float*)d_in[11]; const float* b5 = (const float*)d_in[12];
    const float* W6 = (const float*)d_in[13]; const float* b6 = (const float*)d_in[14];
    float* out = (float*)d_out;

    char* ws = (char*)d_ws;
    size_t off = 0;
    auto carve = [&](size_t bytes) -> void* {
        void* q = ws + off;
        off += (bytes + 255) & ~(size_t)255;
        return q;
    };
    ushort* bufX = (ushort*)carve((size_t)MROWS * 512 * 2);   // activations (GEMM input)
    ushort* bufH = (ushort*)carve((size_t)MROWS * 512 * 2);   // pre-aggregation h
    ushort* Wt2  = (ushort*)carve((size_t)512 * 512 * 2);
    ushort* Wt3  = (ushort*)carve((size_t)512 * 512 * 2);
    ushort* Wt4  = (ushort*)carve((size_t)512 * 512 * 2);
    ushort* Wt5  = (ushort*)carve((size_t)64 * 512 * 2);
    float*  basev = (float*)carve((size_t)BB * 512 * 4);
    int*    deg  = (int*)carve((size_t)NV * 4);
    int*    fill = (int*)carve((size_t)NV * 4);
    float*  dinv = (float*)carve((size_t)NV * 4);
    int*    rp   = (int*)carve((size_t)(NV + 1) * 4);
    int*    ci   = (int*)carve((size_t)(NE + NV) * 4);
    float*  valv = (float*)carve((size_t)(NE + NV) * 4);
    float*  h3   = (float*)carve((size_t)MROWS * 3 * 4);

    dim3 b256(256);
    // CSR build
    k_init<<<dim3((NV + 255) / 256), b256, 0, stream>>>(deg, fill);
    k_count<<<dim3((NE + 255) / 256), b256, 0, stream>>>(ei, deg);
    k_dinv<<<dim3((NV + 255) / 256), b256, 0, stream>>>(deg, dinv);
    k_scan<<<dim3(1), dim3(1024), 0, stream>>>(deg, rp);
    k_fill<<<dim3((NE + NV + 255) / 256), b256, 0, stream>>>(ei, rp, fill, dinv, ci, valv);
    // weights -> bf16 transposed
    k_wconv<<<dim3((512 * 512 + 255) / 256), b256, 0, stream>>>(W2, Wt2, 512, 512);
    k_wconv<<<dim3((512 * 512 + 255) / 256), b256, 0, stream>>>(W3, Wt3, 512, 512);
    k_wconv<<<dim3((512 * 512 + 255) / 256), b256, 0, stream>>>(W4, Wt4, 512, 512);
    k_wconv<<<dim3((512 * 64 + 255) / 256), b256, 0, stream>>>(W5, Wt5, 512, 64);
    // layer 1 (broadcast trick)
    k_l1base<<<dim3(4, BB), dim3(128), 0, stream>>>(img, W1, basev);
    k_l1h<<<dim3((MROWS + 1) / 2), b256, 0, stream>>>(verts, W1, basev, bufH);
    k_aggv<512, 512, false><<<dim3(NV), dim3(512), 0, stream>>>(bufH, bufX, rp, ci, valv, b1);

    // GEMM grids: 8 XCDs * ceil(nrc/8) row chunks * ncb col blocks
    const int nrc = (MROWS + 127) / 128;            // 641
    const int g512 = 8 * ((nrc + 7) / 8) * 4;       // 2592
    const int g64  = 8 * ((nrc + 7) / 8) * 1;       // 648
    // layer 2 (+relu)
    k_gemm<<<dim3(g512), b256, 0, stream>>>(bufX, Wt2, bufH, MROWS, 512);
    k_aggv<512, 512, true><<<dim3(NV), dim3(512), 0, stream>>>(bufH, bufX, rp, ci, valv, b2);
    // layer 3
    k_gemm<<<dim3(g512), b256, 0, stream>>>(bufX, Wt3, bufH, MROWS, 512);
    k_aggv<512, 512, false><<<dim3(NV), dim3(512), 0, stream>>>(bufH, bufX, rp, ci, valv, b3);
    // layer 4 (+relu)
    k_gemm<<<dim3(g512), b256, 0, stream>>>(bufX, Wt4, bufH, MROWS, 512);
    k_aggv<512, 512, true><<<dim3(NV), dim3(512), 0, stream>>>(bufH, bufX, rp, ci, valv, b4);
    // layer 5 (512 -> 64)
    k_gemm<<<dim3(g64), b256, 0, stream>>>(bufX, Wt5, bufH, MROWS, 64);
    k_aggv<64, 64, false><<<dim3(NV), dim3(64), 0, stream>>>(bufH, bufX, rp, ci, valv, b5);
    // layer 6 (64 -> 3, f32) + final aggregation into d_out
    k_l6<<<dim3((MROWS + 255) / 256), b256, 0, stream>>>(bufX, W6, h3);
    k_agg3<<<dim3((MROWS + 255) / 256), b256, 0, stream>>>(h3, out, rp, ci, valv, b6);
}

// Round 5
// 731.782 us; speedup vs baseline: 1.0597x; 1.0597x over previous
//
#include <hip/hip_runtime.h>
#include <hip/hip_bf16.h>

typedef __attribute__((ext_vector_type(8))) short short8_t;
typedef __attribute__((ext_vector_type(4))) float f32x4;

#define DEV __device__ __forceinline__

constexpr int BB = 8;           // batch
constexpr int NV = 10242;       // vertices
constexpr int NE = 61440;       // edges
constexpr int MROWS = BB * NV;  // 81936
constexpr int KD = 512;         // K for layers 1-5

DEV float bf2f(ushort u) { union { unsigned i; float f; } v; v.i = ((unsigned)u) << 16; return v.f; }
DEV ushort f2bf(float f) {
    union { unsigned i; float f; } v; v.f = f;
    unsigned b = v.i;
    b += 0x7fffu + ((b >> 16) & 1u);   // RNE
    return (ushort)(b >> 16);
}

// ---------------- CSR build ----------------
__global__ void k_init(int* deg, int* fill) {
    int i = blockIdx.x * 256 + threadIdx.x;
    if (i < NV) { deg[i] = 1; fill[i] = 0; }   // self-loop counts as 1
}

__global__ void k_count(const int* __restrict__ ei, int* __restrict__ deg) {
    int e = blockIdx.x * 256 + threadIdx.x;
    if (e < NE) atomicAdd(&deg[ei[NE + e]], 1);   // dst row of edge_indices
}

__global__ void k_dinv(const int* __restrict__ deg, float* __restrict__ dinv) {
    int i = blockIdx.x * 256 + threadIdx.x;
    if (i < NV) dinv[i] = rsqrtf((float)deg[i]);
}

__global__ __launch_bounds__(1024) void k_scan(const int* __restrict__ cnt, int* __restrict__ rp) {
    __shared__ int part[1024];
    const int t = threadIdx.x;
    const int chunk = (NV + 1023) / 1024;   // 11
    int b0 = t * chunk, b1 = min(b0 + chunk, NV);
    int s = 0;
    for (int i = b0; i < b1; ++i) s += cnt[i];
    part[t] = s;
    __syncthreads();
    for (int off = 1; off < 1024; off <<= 1) {
        int v = (t >= off) ? part[t - off] : 0;
        __syncthreads();
        part[t] += v;
        __syncthreads();
    }
    int run = (t == 0) ? 0 : part[t - 1];
    for (int i = b0; i < b1; ++i) { rp[i] = run; run += cnt[i]; }
    if (t == 1023) rp[NV] = part[1023];
}

__global__ void k_fill(const int* __restrict__ ei, const int* __restrict__ rp,
                       int* __restrict__ fill, const float* __restrict__ dinv,
                       int* __restrict__ ci, float* __restrict__ val) {
    int e = blockIdx.x * 256 + threadIdx.x;
    if (e >= NE + NV) return;
    int s, d;
    if (e < NE) { s = ei[e]; d = ei[NE + e]; }
    else        { s = d = e - NE; }           // self-loops
    int p = atomicAdd(&fill[d], 1);
    int pos = rp[d] + p;
    ci[pos] = s;
    val[pos] = dinv[s] * dinv[d];
}

// ---------------- weight convert / transpose:  Wt[n][k] = bf16(W[k][n]) ----------------
__global__ void k_wconv(const float* __restrict__ W, ushort* __restrict__ Wt, int Kd, int Nc) {
    int idx = blockIdx.x * 256 + threadIdx.x;
    if (idx >= Kd * Nc) return;
    int n = idx / Kd, k = idx - n * Kd;
    Wt[idx] = f2bf(W[(size_t)k * Nc + n]);
}

// ---------------- layer 1 ----------------
// base[b][c] = sum_k img[b][k] * W1[3+k][c]
__global__ __launch_bounds__(128) void k_l1base(const float* __restrict__ img, const float* __restrict__ W1,
                                                float* __restrict__ base) {
    int c = blockIdx.x * 128 + threadIdx.x;   // grid.x = 4
    int b = blockIdx.y;
    float s = 0.f;
    for (int k = 0; k < 512; ++k) s = fmaf(img[b * 512 + k], W1[(size_t)(3 + k) * 512 + c], s);
    base[b * 512 + c] = s;
}

// h[row(i,b), c], vertex-major: row = i*BB + b. 2 rows per 256-thread block.
__global__ __launch_bounds__(256) void k_l1h(const float* __restrict__ verts, const float* __restrict__ W1,
                                             const float* __restrict__ base, ushort* __restrict__ h) {
    const int t = threadIdx.x;
    int row = blockIdx.x * 2 + (t >> 7);       // activation row = i*BB + b
    if (row >= MROWS) return;
    int i = row >> 3, b = row & 7;
    size_t vrow = (size_t)b * NV + i;          // input order [B][N][3]
    float v0 = verts[vrow * 3 + 0], v1 = verts[vrow * 3 + 1], v2 = verts[vrow * 3 + 2];
    int c = (t & 127) * 4;
    float4 w0 = *(const float4*)&W1[c];
    float4 w1 = *(const float4*)&W1[512 + c];
    float4 w2 = *(const float4*)&W1[1024 + c];
    float4 bs = *(const float4*)&base[b * 512 + c];
    ushort4 o;
    o.x = f2bf(v0 * w0.x + v1 * w1.x + v2 * w2.x + bs.x);
    o.y = f2bf(v0 * w0.y + v1 * w1.y + v2 * w2.y + bs.y);
    o.z = f2bf(v0 * w0.z + v1 * w1.z + v2 * w2.z + bs.z);
    o.w = f2bf(v0 * w0.w + v1 * w1.w + v2 * w2.w + bs.w);
    *(ushort4*)&h[(size_t)row * 512 + c] = o;
}

// ---------------- GEMM: C[M,Nc] = A[M,512] @ Wt[Nc,512]^T  (bf16 in, bf16 out, f32 acc) ----------------
// 1-D grid, XCD row-affinity: all column-blocks of a row-chunk land on the same XCD
// (bid%8 round-robin heuristic) so the A-chunk is read from HBM once per XCD.
__global__ __launch_bounds__(256) void k_gemm(const ushort* __restrict__ A, const ushort* __restrict__ Bt,
                                              ushort* __restrict__ C, int Mr, int Nc) {
    const int ncb = (Nc + 127) >> 7;           // column blocks
    const int nrc = (Mr + 127) >> 7;           // row chunks
    const int cpx = (nrc + 7) >> 3;            // row chunks per XCD (ceil)
    const int bid = blockIdx.x;
    const int xcd = bid & 7;
    const int k = bid >> 3;                    // 0 .. cpx*ncb-1
    const int rc = xcd * cpx + k / ncb;
    const int cb = k % ncb;
    if (rc >= nrc) return;

    __shared__ __align__(16) ushort lA[2][4096];   // [128 rows][32 k]
    __shared__ __align__(16) ushort lB[2][4096];   // [128 cols][32 k]
    const int t = threadIdx.x;
    const int lane = t & 63, w = t >> 6;
    const int wr = w >> 1, wc = w & 1;
    const int r0 = rc * 128, c0 = cb * 128;

    const ushort* gA[2]; const ushort* gB[2];
    int ldsoff[2];
    #pragma unroll
    for (int i2 = 0; i2 < 2; ++i2) {
        int idx = i2 * 256 + t;
        int row = idx >> 2, slot = idx & 3;
        int ar = min(r0 + row, Mr - 1);
        int bc = min(c0 + row, Nc - 1);
        gA[i2] = A + (size_t)ar * KD + slot * 8;
        gB[i2] = Bt + (size_t)bc * KD + slot * 8;
        ldsoff[i2] = i2 * 2048 + w * 512;   // elements; wave-uniform
    }

    auto stage = [&](int buf, int kt) {
        int ko = kt * 32;
        #pragma unroll
        for (int i2 = 0; i2 < 2; ++i2) {
            __builtin_amdgcn_global_load_lds(
                (const __attribute__((address_space(1))) void*)(gA[i2] + ko),
                (__attribute__((address_space(3))) void*)(&lA[buf][ldsoff[i2]]), 16, 0, 0);
            __builtin_amdgcn_global_load_lds(
                (const __attribute__((address_space(1))) void*)(gB[i2] + ko),
                (__attribute__((address_space(3))) void*)(&lB[buf][ldsoff[i2]]), 16, 0, 0);
        }
    };

    f32x4 acc[4][4] = {};
    stage(0, 0);
    __syncthreads();
    int cur = 0;
    const int kslot = (lane >> 4) * 8;
    const int rloc = lane & 15;
    for (int kt = 0; kt < 16; ++kt) {
        if (kt < 15) stage(cur ^ 1, kt + 1);
        short8_t af[4], bfr[4];
        #pragma unroll
        for (int m = 0; m < 4; ++m) {
            af[m]  = *(const short8_t*)&lA[cur][(wr * 64 + m * 16 + rloc) * 32 + kslot];
            bfr[m] = *(const short8_t*)&lB[cur][(wc * 64 + m * 16 + rloc) * 32 + kslot];
        }
        #pragma unroll
        for (int m = 0; m < 4; ++m)
            #pragma unroll
            for (int n = 0; n < 4; ++n)
                acc[m][n] = __builtin_amdgcn_mfma_f32_16x16x32_bf16(af[m], bfr[n], acc[m][n], 0, 0, 0);
        __syncthreads();
        cur ^= 1;
    }

    const int orow = r0 + wr * 64 + (lane >> 4) * 4;
    const int ocol = c0 + wc * 64 + rloc;
    #pragma unroll
    for (int m = 0; m < 4; ++m) {
        #pragma unroll
        for (int n = 0; n < 4; ++n) {
            int gc = ocol + n * 16;
            if (gc >= Nc) continue;
            #pragma unroll
            for (int r = 0; r < 4; ++r) {
                int gr = orow + m * 16 + r;
                if (gr < Mr) C[(size_t)gr * Nc + gc] = f2bf(acc[m][n][r]);
            }
        }
    }
}

// ---------------- vertex-major batch-fused aggregation, 8 vertices/block ----------------
// Block owns vertices [i0, i0+8): contiguous CSR edge range [rp[i0], rp[i0+8]).
// All ci/val preloaded to LDS once -> index fetch off the global critical path;
// 8 sequential vertices per block amortize launch/prologue and give the
// scheduler continuous independent gather work. Thread t owns 16B of the 8KB
// per-edge chunk; 4-deep zero-padded edge pipeline.
template <bool RELU>
__global__ __launch_bounds__(512) void k_aggv8(const ushort* __restrict__ h, ushort* __restrict__ xo,
                                               const int* __restrict__ rp, const int* __restrict__ ci,
                                               const float* __restrict__ val, const float* __restrict__ bias) {
    constexpr int CH = BB * 512;              // 4096 elements per vertex chunk
    constexpr int CAP = 1024;                 // LDS edge capacity (max group deg ~80)
    __shared__ int   sj[CAP];
    __shared__ float sw[CAP];
    __shared__ int   srp[9];
    const int t = threadIdx.x;
    const int i0 = blockIdx.x * 8;
    if (t < 9) srp[t] = rp[min(i0 + t, NV)];
    __syncthreads();
    const int e0 = srp[0];
    const int cnt = srp[8] - e0;
    for (int e = t; e < cnt && e < CAP; e += 512) { sj[e] = ci[e0 + e]; sw[e] = val[e0 + e]; }
    __syncthreads();

    const ushort* hb = h + t * 8;
    const int fb = (t * 8) & 511;
    const float4 bl = *(const float4*)&bias[fb];
    const float4 bh = *(const float4*)&bias[fb + 4];
    const float bb[8] = {bl.x, bl.y, bl.z, bl.w, bh.x, bh.y, bh.z, bh.w};

    for (int v = 0; v < 8; ++v) {
        const int i = i0 + v;
        if (i >= NV) break;                   // block-uniform
        const int r0 = srp[v] - e0, r1 = srp[v + 1] - e0;
        float acc[8] = {};
        for (int e = r0; e < r1; e += 4) {
            const bool p1 = e + 1 < r1, p2 = e + 2 < r1, p3 = e + 3 < r1;
            int j0, j1, j2, j3; float w0, w1, w2, w3;
            if (e < CAP) { j0 = sj[e]; w0 = sw[e]; } else { j0 = ci[e0 + e]; w0 = val[e0 + e]; }
            j1 = j0; j2 = j0; j3 = j0; w1 = 0.f; w2 = 0.f; w3 = 0.f;
            if (p1) { if (e + 1 < CAP) { j1 = sj[e + 1]; w1 = sw[e + 1]; } else { j1 = ci[e0 + e + 1]; w1 = val[e0 + e + 1]; } }
            if (p2) { if (e + 2 < CAP) { j2 = sj[e + 2]; w2 = sw[e + 2]; } else { j2 = ci[e0 + e + 2]; w2 = val[e0 + e + 2]; } }
            if (p3) { if (e + 3 < CAP) { j3 = sj[e + 3]; w3 = sw[e + 3]; } else { j3 = ci[e0 + e + 3]; w3 = val[e0 + e + 3]; } }
            const short8_t v0 = *(const short8_t*)(hb + (size_t)j0 * CH);
            const short8_t v1 = *(const short8_t*)(hb + (size_t)j1 * CH);
            const short8_t v2 = *(const short8_t*)(hb + (size_t)j2 * CH);
            const short8_t v3 = *(const short8_t*)(hb + (size_t)j3 * CH);
            #pragma unroll
            for (int k = 0; k < 8; ++k) {
                float a = acc[k];
                a = fmaf(w0, bf2f((ushort)v0[k]), a);
                a = fmaf(w1, bf2f((ushort)v1[k]), a);
                a = fmaf(w2, bf2f((ushort)v2[k]), a);
                a = fmaf(w3, bf2f((ushort)v3[k]), a);
                acc[k] = a;
            }
        }
        short8_t o;
        #pragma unroll
        for (int k = 0; k < 8; ++k) {
            float a = acc[k] + bb[k];
            if (RELU) a = fmaxf(a, 0.f);
            o[k] = (short)f2bf(a);
        }
        *(short8_t*)(xo + (size_t)i * CH + t * 8) = o;
    }
}

// ---------------- F=64 aggregation (layer 5 output), one block=one vertex ----------------
template <int F, int NT, bool RELU>
__global__ __launch_bounds__(NT) void k_aggv(const ushort* __restrict__ h, ushort* __restrict__ xo,
                                             const int* __restrict__ rp, const int* __restrict__ ci,
                                             const float* __restrict__ val, const float* __restrict__ bias) {
    constexpr int CH = BB * F;
    static_assert(NT * 8 == CH, "one short8 per thread");
    const int i = blockIdx.x;
    const int t = threadIdx.x;
    const int r0 = rp[i], r1 = rp[i + 1];
    const ushort* hb = h + t * 8;
    float acc[8] = {};
    for (int e = r0; e < r1; e += 4) {
        const bool p1 = e + 1 < r1, p2 = e + 2 < r1, p3 = e + 3 < r1;
        const int j0 = ci[e];
        const int j1 = p1 ? ci[e + 1] : j0;
        const int j2 = p2 ? ci[e + 2] : j0;
        const int j3 = p3 ? ci[e + 3] : j0;
        const float w0 = val[e];
        const float w1 = p1 ? val[e + 1] : 0.f;
        const float w2 = p2 ? val[e + 2] : 0.f;
        const float w3 = p3 ? val[e + 3] : 0.f;
        const short8_t v0 = *(const short8_t*)(hb + (size_t)j0 * CH);
        const short8_t v1 = *(const short8_t*)(hb + (size_t)j1 * CH);
        const short8_t v2 = *(const short8_t*)(hb + (size_t)j2 * CH);
        const short8_t v3 = *(const short8_t*)(hb + (size_t)j3 * CH);
        #pragma unroll
        for (int k = 0; k < 8; ++k) {
            float a = acc[k];
            a = fmaf(w0, bf2f((ushort)v0[k]), a);
            a = fmaf(w1, bf2f((ushort)v1[k]), a);
            a = fmaf(w2, bf2f((ushort)v2[k]), a);
            a = fmaf(w3, bf2f((ushort)v3[k]), a);
            acc[k] = a;
        }
    }
    const int fb = (t * 8) & (F - 1);
    const float4 bl = *(const float4*)&bias[fb];
    const float4 bh = *(const float4*)&bias[fb + 4];
    const float bb[8] = {bl.x, bl.y, bl.z, bl.w, bh.x, bh.y, bh.z, bh.w};
    short8_t o;
    #pragma unroll
    for (int k = 0; k < 8; ++k) {
        float a = acc[k] + bb[k];
        if (RELU) a = fmaxf(a, 0.f);
        o[k] = (short)f2bf(a);
    }
    *(short8_t*)(xo + (size_t)i * CH + t * 8) = o;
}

// ---------------- layer 6: h3 = x64 @ W6 (64x3, f32), rows vertex-major ----------------
__global__ __launch_bounds__(256) void k_l6(const ushort* __restrict__ x64, const float* __restrict__ W6,
                                            float* __restrict__ h3) {
    __shared__ float w[192];
    if (threadIdx.x < 192) w[threadIdx.x] = W6[threadIdx.x];
    __syncthreads();
    int r = blockIdx.x * 256 + threadIdx.x;
    if (r >= MROWS) return;
    const ushort* xr = x64 + (size_t)r * 64;
    float a0 = 0, a1 = 0, a2 = 0;
    #pragma unroll 8
    for (int k = 0; k < 64; ++k) {
        float xv = bf2f(xr[k]);
        a0 = fmaf(xv, w[k * 3 + 0], a0);
        a1 = fmaf(xv, w[k * 3 + 1], a1);
        a2 = fmaf(xv, w[k * 3 + 2], a2);
    }
    float* o = h3 + (size_t)r * 3;
    o[0] = a0; o[1] = a1; o[2] = a2;
}

// final aggregation: h3 vertex-major [i*8+b][3] -> out [b][i][3]
__global__ __launch_bounds__(256) void k_agg3(const float* __restrict__ h3, float* __restrict__ out,
                                              const int* __restrict__ rp, const int* __restrict__ ci,
                                              const float* __restrict__ val, const float* __restrict__ b6) {
    int idx = blockIdx.x * 256 + threadIdx.x;
    if (idx >= MROWS) return;
    int b = idx / NV, i = idx - b * NV;
    float a0 = b6[0], a1 = b6[1], a2 = b6[2];
    int r0 = rp[i], r1 = rp[i + 1];
    for (int e = r0; e < r1; ++e) {
        int j = ci[e];
        float wv = val[e];
        const float* hr = h3 + ((size_t)j * BB + b) * 3;
        a0 = fmaf(wv, hr[0], a0);
        a1 = fmaf(wv, hr[1], a1);
        a2 = fmaf(wv, hr[2], a2);
    }
    float* o = out + (size_t)idx * 3;
    o[0] = a0; o[1] = a1; o[2] = a2;
}

// ---------------- launcher ----------------
extern "C" void kernel_launch(void* const* d_in, const int* in_sizes, int n_in,
                              void* d_out, int out_size, void* d_ws, size_t ws_size,
                              hipStream_t stream) {
    const float* verts = (const float*)d_in[0];
    const float* img   = (const float*)d_in[1];
    const int*   ei    = (const int*)d_in[2];
    const float* W1 = (const float*)d_in[3];  const float* b1 = (const float*)d_in[4];
    const float* W2 = (const float*)d_in[5];  const float* b2 = (const float*)d_in[6];
    const float* W3 = (const float*)d_in[7];  const float* b3 = (const float*)d_in[8];
    const float* W4 = (const float*)d_in[9];  const float* b4 = (const float*)d_in[10];
    const float* W5 = (const float*)d_in[11]; const float* b5 = (const float*)d_in[12];
    const float* W6 = (const float*)d_in[13]; const float* b6 = (const float*)d_in[14];
    float* out = (float*)d_out;

    char* ws = (char*)d_ws;
    size_t off = 0;
    auto carve = [&](size_t bytes) -> void* {
        void* q = ws + off;
        off += (bytes + 255) & ~(size_t)255;
        return q;
    };
    ushort* bufX = (ushort*)carve((size_t)MROWS * 512 * 2);   // activations (GEMM input)
    ushort* bufH = (ushort*)carve((size_t)MROWS * 512 * 2);   // pre-aggregation h
    ushort* Wt2  = (ushort*)carve((size_t)512 * 512 * 2);
    ushort* Wt3  = (ushort*)carve((size_t)512 * 512 * 2);
    ushort* Wt4  = (ushort*)carve((size_t)512 * 512 * 2);
    ushort* Wt5  = (ushort*)carve((size_t)64 * 512 * 2);
    float*  basev = (float*)carve((size_t)BB * 512 * 4);
    int*    deg  = (int*)carve((size_t)NV * 4);
    int*    fill = (int*)carve((size_t)NV * 4);
    float*  dinv = (float*)carve((size_t)NV * 4);
    int*    rp   = (int*)carve((size_t)(NV + 1) * 4);
    int*    ci   = (int*)carve((size_t)(NE + NV) * 4);
    float*  valv = (float*)carve((size_t)(NE + NV) * 4);
    float*  h3   = (float*)carve((size_t)MROWS * 3 * 4);

    dim3 b256(256);
    // CSR build
    k_init<<<dim3((NV + 255) / 256), b256, 0, stream>>>(deg, fill);
    k_count<<<dim3((NE + 255) / 256), b256, 0, stream>>>(ei, deg);
    k_dinv<<<dim3((NV + 255) / 256), b256, 0, stream>>>(deg, dinv);
    k_scan<<<dim3(1), dim3(1024), 0, stream>>>(deg, rp);
    k_fill<<<dim3((NE + NV + 255) / 256), b256, 0, stream>>>(ei, rp, fill, dinv, ci, valv);
    // weights -> bf16 transposed
    k_wconv<<<dim3((512 * 512 + 255) / 256), b256, 0, stream>>>(W2, Wt2, 512, 512);
    k_wconv<<<dim3((512 * 512 + 255) / 256), b256, 0, stream>>>(W3, Wt3, 512, 512);
    k_wconv<<<dim3((512 * 512 + 255) / 256), b256, 0, stream>>>(W4, Wt4, 512, 512);
    k_wconv<<<dim3((512 * 64 + 255) / 256), b256, 0, stream>>>(W5, Wt5, 512, 64);
    // layer 1 (broadcast trick)
    k_l1base<<<dim3(4, BB), dim3(128), 0, stream>>>(img, W1, basev);
    k_l1h<<<dim3((MROWS + 1) / 2), b256, 0, stream>>>(verts, W1, basev, bufH);
    const int nagg8 = (NV + 7) / 8;   // 1281
    k_aggv8<false><<<dim3(nagg8), dim3(512), 0, stream>>>(bufH, bufX, rp, ci, valv, b1);

    // GEMM grids: 8 XCDs * ceil(nrc/8) row chunks * ncb col blocks
    const int nrc = (MROWS + 127) / 128;            // 641
    const int g512 = 8 * ((nrc + 7) / 8) * 4;       // 2592
    const int g64  = 8 * ((nrc + 7) / 8) * 1;       // 648
    // layer 2 (+relu)
    k_gemm<<<dim3(g512), b256, 0, stream>>>(bufX, Wt2, bufH, MROWS, 512);
    k_aggv8<true><<<dim3(nagg8), dim3(512), 0, stream>>>(bufH, bufX, rp, ci, valv, b2);
    // layer 3
    k_gemm<<<dim3(g512), b256, 0, stream>>>(bufX, Wt3, bufH, MROWS, 512);
    k_aggv8<false><<<dim3(nagg8), dim3(512), 0, stream>>>(bufH, bufX, rp, ci, valv, b3);
    // layer 4 (+relu)
    k_gemm<<<dim3(g512), b256, 0, stream>>>(bufX, Wt4, bufH, MROWS, 512);
    k_aggv8<true><<<dim3(nagg8), dim3(512), 0, stream>>>(bufH, bufX, rp, ci, valv, b4);
    // layer 5 (512 -> 64)
    k_gemm<<<dim3(g64), b256, 0, stream>>>(bufX, Wt5, bufH, MROWS, 64);
    k_aggv<64, 64, false><<<dim3(NV), dim3(64), 0, stream>>>(bufH, bufX, rp, ci, valv, b5);
    // layer 6 (64 -> 3, f32) + final aggregation into d_out
    k_l6<<<dim3((MROWS + 255) / 256), b256, 0, stream>>>(bufX, W6, h3);
    k_agg3<<<dim3((MROWS + 255) / 256), b256, 0, stream>>>(h3, out, rp, ci, valv, b6);
}

// Round 6
// 561.095 us; speedup vs baseline: 1.3821x; 1.3042x over previous
//
#include <hip/hip_runtime.h>
#include <hip/hip_bf16.h>

typedef __attribute__((ext_vector_type(8))) short short8_t;
typedef __attribute__((ext_vector_type(4))) float f32x4;

#define DEV __device__ __forceinline__

constexpr int BB = 8;           // batch
constexpr int NV = 10242;       // vertices
constexpr int NE = 61440;       // edges
constexpr int MROWS = BB * NV;  // 81936
constexpr int KD = 512;         // K for 512-wide GEMMs

DEV float bf2f(ushort u) { union { unsigned i; float f; } v; v.i = ((unsigned)u) << 16; return v.f; }
DEV ushort f2bf(float f) {
    union { unsigned i; float f; } v; v.f = f;
    unsigned b = v.i;
    b += 0x7fffu + ((b >> 16) & 1u);   // RNE
    return (ushort)(b >> 16);
}

// ---------------- CSR build ----------------
__global__ void k_init(int* deg, int* fill) {
    int i = blockIdx.x * 256 + threadIdx.x;
    if (i < NV) { deg[i] = 1; fill[i] = 0; }   // self-loop counts as 1
}

__global__ void k_count(const int* __restrict__ ei, int* __restrict__ deg) {
    int e = blockIdx.x * 256 + threadIdx.x;
    if (e < NE) atomicAdd(&deg[ei[NE + e]], 1);   // dst row
}

__global__ void k_dinv(const int* __restrict__ deg, float* __restrict__ dinv) {
    int i = blockIdx.x * 256 + threadIdx.x;
    if (i < NV) dinv[i] = rsqrtf((float)deg[i]);
}

__global__ __launch_bounds__(1024) void k_scan(const int* __restrict__ cnt, int* __restrict__ rp) {
    __shared__ int part[1024];
    const int t = threadIdx.x;
    const int chunk = (NV + 1023) / 1024;   // 11
    int b0 = t * chunk, b1 = min(b0 + chunk, NV);
    int s = 0;
    for (int i = b0; i < b1; ++i) s += cnt[i];
    part[t] = s;
    __syncthreads();
    for (int off = 1; off < 1024; off <<= 1) {
        int v = (t >= off) ? part[t - off] : 0;
        __syncthreads();
        part[t] += v;
        __syncthreads();
    }
    int run = (t == 0) ? 0 : part[t - 1];
    for (int i = b0; i < b1; ++i) { rp[i] = run; run += cnt[i]; }
    if (t == 1023) rp[NV] = part[1023];
}

__global__ void k_fill(const int* __restrict__ ei, const int* __restrict__ rp,
                       int* __restrict__ fill, const float* __restrict__ dinv,
                       int* __restrict__ ci, float* __restrict__ val) {
    int e = blockIdx.x * 256 + threadIdx.x;
    if (e >= NE + NV) return;
    int s, d;
    if (e < NE) { s = ei[e]; d = ei[NE + e]; }
    else        { s = d = e - NE; }           // self-loops
    int p = atomicAdd(&fill[d], 1);
    int pos = rp[d] + p;
    ci[pos] = s;
    val[pos] = dinv[s] * dinv[d];
}

// s[i] = row-sum of A  (= A*ones)
__global__ void k_srow(const int* __restrict__ rp, const float* __restrict__ val, float* __restrict__ s) {
    int i = blockIdx.x * 256 + threadIdx.x;
    if (i >= NV) return;
    float a = 0.f;
    for (int e = rp[i]; e < rp[i + 1]; ++e) a += val[e];
    s[i] = a;
}

// s2 = A*s
__global__ void k_s2(const int* __restrict__ rp, const int* __restrict__ ci,
                     const float* __restrict__ val, const float* __restrict__ s, float* __restrict__ s2) {
    int i = blockIdx.x * 256 + threadIdx.x;
    if (i >= NV) return;
    float a = 0.f;
    for (int e = rp[i]; e < rp[i + 1]; ++e) a += val[e] * s[ci[e]];
    s2[i] = a;
}

// 3-wide sparse agg, batch-major [b][n][3] f32 -> same layout (used for verts and aggV)
__global__ __launch_bounds__(256) void k_aggsm(const float* __restrict__ src, float* __restrict__ dst,
                                               const int* __restrict__ rp, const int* __restrict__ ci,
                                               const float* __restrict__ val) {
    int idx = blockIdx.x * 256 + threadIdx.x;
    if (idx >= MROWS) return;
    int b = idx / NV, i = idx - b * NV;
    float a0 = 0.f, a1 = 0.f, a2 = 0.f;
    const float* sb = src + (size_t)b * NV * 3;
    for (int e = rp[i]; e < rp[i + 1]; ++e) {
        int j = ci[e];
        float wv = val[e];
        a0 = fmaf(wv, sb[j * 3 + 0], a0);
        a1 = fmaf(wv, sb[j * 3 + 1], a1);
        a2 = fmaf(wv, sb[j * 3 + 2], a2);
    }
    float* o = dst + ((size_t)b * NV + i) * 3;
    o[0] = a0; o[1] = a1; o[2] = a2;
}

// ---------------- weight prep ----------------
// transpose + cast: Wt[n][k] = bf16(W[k][n])
__global__ void k_wconv(const float* __restrict__ W, ushort* __restrict__ Wt, int Kd, int Nc) {
    int idx = blockIdx.x * 256 + threadIdx.x;
    if (idx >= Kd * Nc) return;
    int n = idx / Kd, k = idx - n * Kd;
    Wt[idx] = f2bf(W[(size_t)k * Nc + n]);
}

// plain cast, no transpose
__global__ void k_wcast(const float* __restrict__ W, ushort* __restrict__ Wc, int n) {
    int idx = blockIdx.x * 256 + threadIdx.x;
    if (idx < n) Wc[idx] = f2bf(W[idx]);
}

// out[r][c] = sum_k M[r*512+k] * W[k*512+c]   (tiny f32 mat-mat, rows<=8)
__global__ __launch_bounds__(128) void k_matvecs(const float* __restrict__ M, const float* __restrict__ W,
                                                 float* __restrict__ out) {
    int c = blockIdx.x * 128 + threadIdx.x;   // grid.x = 4
    int r = blockIdx.y;
    float a = 0.f;
    for (int k = 0; k < 512; ++k) a = fmaf(M[r * 512 + k], W[(size_t)k * 512 + c], a);
    out[r * 512 + c] = a;
}

// base[b][c] = sum_k img[b][k] * W1[3+k][c]
__global__ __launch_bounds__(128) void k_l1base(const float* __restrict__ img, const float* __restrict__ W1,
                                                float* __restrict__ base) {
    int c = blockIdx.x * 128 + threadIdx.x;   // grid.x = 4
    int b = blockIdx.y;
    float s = 0.f;
    for (int k = 0; k < 512; ++k) s = fmaf(img[b * 512 + k], W1[(size_t)(3 + k) * 512 + c], s);
    base[b * 512 + c] = s;
}

// ---------------- x2 reconstruction (layers 1-2 collapsed) ----------------
// r2[i*8+b][c] = relu( sum_k aggV2[b][i][k]*CW12[k][c] + s2[i]*bw2[b][c] + s[i]*b1w2[c] + b2[c] )
__global__ __launch_bounds__(256) void k_x2(const float* __restrict__ aggV2, const float* __restrict__ s,
                                            const float* __restrict__ s2, const float* __restrict__ CW12,
                                            const float* __restrict__ bw2, const float* __restrict__ b1w2,
                                            const float* __restrict__ b2, ushort* __restrict__ r2) {
    const int t = threadIdx.x;
    int row = blockIdx.x * 2 + (t >> 7);
    if (row >= MROWS) return;
    int i = row >> 3, b = row & 7;
    const float* av = aggV2 + ((size_t)b * NV + i) * 3;
    float a0 = av[0], a1 = av[1], a2 = av[2];
    float si = s[i], s2i = s2[i];
    int c = (t & 127) * 4;
    float4 w0 = *(const float4*)&CW12[c];
    float4 w1 = *(const float4*)&CW12[512 + c];
    float4 w2 = *(const float4*)&CW12[1024 + c];
    float4 bw = *(const float4*)&bw2[b * 512 + c];
    float4 bv = *(const float4*)&b1w2[c];
    float4 b2v = *(const float4*)&b2[c];
    float o0 = a0 * w0.x + a1 * w1.x + a2 * w2.x + s2i * bw.x + si * bv.x + b2v.x;
    float o1 = a0 * w0.y + a1 * w1.y + a2 * w2.y + s2i * bw.y + si * bv.y + b2v.y;
    float o2 = a0 * w0.z + a1 * w1.z + a2 * w2.z + s2i * bw.z + si * bv.z + b2v.z;
    float o3 = a0 * w0.w + a1 * w1.w + a2 * w2.w + s2i * bw.w + si * bv.w + b2v.w;
    ushort4 o;
    o.x = f2bf(fmaxf(o0, 0.f));
    o.y = f2bf(fmaxf(o1, 0.f));
    o.z = f2bf(fmaxf(o2, 0.f));
    o.w = f2bf(fmaxf(o3, 0.f));
    *(ushort4*)&r2[(size_t)row * 512 + c] = o;
}

// ---------------- GEMM: C[M,Nc] = A[M,512] @ Bt[Nc,512]^T  (bf16 in, bf16 out, f32 acc) ----------------
// EPI=0: plain.  EPI=1: v += sv[row/8]*eb1[col] + eb2[col]; relu.  (XCD row-affinity 1-D grid)
template <int EPI>
__global__ __launch_bounds__(256) void k_gemm(const ushort* __restrict__ A, const ushort* __restrict__ Bt,
                                              ushort* __restrict__ C, int Mr, int Nc,
                                              const float* __restrict__ sv, const float* __restrict__ eb1,
                                              const float* __restrict__ eb2) {
    const int ncb = (Nc + 127) >> 7;
    const int nrc = (Mr + 127) >> 7;
    const int cpx = (nrc + 7) >> 3;
    const int bid = blockIdx.x;
    const int xcd = bid & 7;
    const int k = bid >> 3;
    const int rc = xcd * cpx + k / ncb;
    const int cb = k % ncb;
    if (rc >= nrc) return;

    __shared__ __align__(16) ushort lA[2][4096];
    __shared__ __align__(16) ushort lB[2][4096];
    const int t = threadIdx.x;
    const int lane = t & 63, w = t >> 6;
    const int wr = w >> 1, wc = w & 1;
    const int r0 = rc * 128, c0 = cb * 128;

    const ushort* gA[2]; const ushort* gB[2];
    int ldsoff[2];
    #pragma unroll
    for (int i2 = 0; i2 < 2; ++i2) {
        int idx = i2 * 256 + t;
        int row = idx >> 2, slot = idx & 3;
        int ar = min(r0 + row, Mr - 1);
        int bc = min(c0 + row, Nc - 1);
        gA[i2] = A + (size_t)ar * KD + slot * 8;
        gB[i2] = Bt + (size_t)bc * KD + slot * 8;
        ldsoff[i2] = i2 * 2048 + w * 512;
    }

    auto stage = [&](int buf, int kt) {
        int ko = kt * 32;
        #pragma unroll
        for (int i2 = 0; i2 < 2; ++i2) {
            __builtin_amdgcn_global_load_lds(
                (const __attribute__((address_space(1))) void*)(gA[i2] + ko),
                (__attribute__((address_space(3))) void*)(&lA[buf][ldsoff[i2]]), 16, 0, 0);
            __builtin_amdgcn_global_load_lds(
                (const __attribute__((address_space(1))) void*)(gB[i2] + ko),
                (__attribute__((address_space(3))) void*)(&lB[buf][ldsoff[i2]]), 16, 0, 0);
        }
    };

    f32x4 acc[4][4] = {};
    stage(0, 0);
    __syncthreads();
    int cur = 0;
    const int kslot = (lane >> 4) * 8;
    const int rloc = lane & 15;
    for (int kt = 0; kt < 16; ++kt) {
        if (kt < 15) stage(cur ^ 1, kt + 1);
        short8_t af[4], bfr[4];
        #pragma unroll
        for (int m = 0; m < 4; ++m) {
            af[m]  = *(const short8_t*)&lA[cur][(wr * 64 + m * 16 + rloc) * 32 + kslot];
            bfr[m] = *(const short8_t*)&lB[cur][(wc * 64 + m * 16 + rloc) * 32 + kslot];
        }
        #pragma unroll
        for (int m = 0; m < 4; ++m)
            #pragma unroll
            for (int n = 0; n < 4; ++n)
                acc[m][n] = __builtin_amdgcn_mfma_f32_16x16x32_bf16(af[m], bfr[n], acc[m][n], 0, 0, 0);
        __syncthreads();
        cur ^= 1;
    }

    const int orow = r0 + wr * 64 + (lane >> 4) * 4;
    const int ocol = c0 + wc * 64 + rloc;
    #pragma unroll
    for (int m = 0; m < 4; ++m) {
        #pragma unroll
        for (int n = 0; n < 4; ++n) {
            int gc = ocol + n * 16;
            if (gc >= Nc) continue;
            #pragma unroll
            for (int r = 0; r < 4; ++r) {
                int gr = orow + m * 16 + r;
                if (gr >= Mr) continue;
                float v = acc[m][n][r];
                if (EPI == 1) {
                    v += sv[gr >> 3] * eb1[gc] + eb2[gc];
                    v = fmaxf(v, 0.f);
                }
                C[(size_t)gr * Nc + gc] = f2bf(v);
            }
        }
    }
}

// ---------------- vertex-major batch-fused aggregation ----------------
// One block per vertex; thread t owns 16B of the 8*F chunk; 4-deep zero-padded
// edge pipeline. BIAS/RELU compile-time.
template <int F, int NT, bool BIAS, bool RELU>
__global__ __launch_bounds__(NT) void k_aggv(const ushort* __restrict__ h, ushort* __restrict__ xo,
                                             const int* __restrict__ rp, const int* __restrict__ ci,
                                             const float* __restrict__ val, const float* __restrict__ bias) {
    constexpr int CH = BB * F;
    static_assert(NT * 8 == CH, "one short8 per thread");
    const int i = blockIdx.x;
    const int t = threadIdx.x;
    const int r0 = rp[i], r1 = rp[i + 1];
    const ushort* hb = h + t * 8;
    float acc[8] = {};
    for (int e = r0; e < r1; e += 4) {
        const bool p1 = e + 1 < r1, p2 = e + 2 < r1, p3 = e + 3 < r1;
        const int j0 = ci[e];
        const int j1 = p1 ? ci[e + 1] : j0;
        const int j2 = p2 ? ci[e + 2] : j0;
        const int j3 = p3 ? ci[e + 3] : j0;
        const float w0 = val[e];
        const float w1 = p1 ? val[e + 1] : 0.f;
        const float w2 = p2 ? val[e + 2] : 0.f;
        const float w3 = p3 ? val[e + 3] : 0.f;
        const short8_t v0 = *(const short8_t*)(hb + (size_t)j0 * CH);
        const short8_t v1 = *(const short8_t*)(hb + (size_t)j1 * CH);
        const short8_t v2 = *(const short8_t*)(hb + (size_t)j2 * CH);
        const short8_t v3 = *(const short8_t*)(hb + (size_t)j3 * CH);
        #pragma unroll
        for (int k = 0; k < 8; ++k) {
            float a = acc[k];
            a = fmaf(w0, bf2f((ushort)v0[k]), a);
            a = fmaf(w1, bf2f((ushort)v1[k]), a);
            a = fmaf(w2, bf2f((ushort)v2[k]), a);
            a = fmaf(w3, bf2f((ushort)v3[k]), a);
            acc[k] = a;
        }
    }
    float bb[8] = {0, 0, 0, 0, 0, 0, 0, 0};
    if (BIAS) {
        const int fb = (t * 8) & (F - 1);
        const float4 bl = *(const float4*)&bias[fb];
        const float4 bh = *(const float4*)&bias[fb + 4];
        bb[0] = bl.x; bb[1] = bl.y; bb[2] = bl.z; bb[3] = bl.w;
        bb[4] = bh.x; bb[5] = bh.y; bb[6] = bh.z; bb[7] = bh.w;
    }
    short8_t o;
    #pragma unroll
    for (int k = 0; k < 8; ++k) {
        float a = acc[k] + bb[k];
        if (RELU) a = fmaxf(a, 0.f);
        o[k] = (short)f2bf(a);
    }
    *(short8_t*)(xo + (size_t)i * CH + t * 8) = o;
}

// ---------------- layer 6: h3 = x64 @ W6 (64x3, f32), rows vertex-major ----------------
__global__ __launch_bounds__(256) void k_l6(const ushort* __restrict__ x64, const float* __restrict__ W6,
                                            float* __restrict__ h3) {
    __shared__ float w[192];
    if (threadIdx.x < 192) w[threadIdx.x] = W6[threadIdx.x];
    __syncthreads();
    int r = blockIdx.x * 256 + threadIdx.x;
    if (r >= MROWS) return;
    const ushort* xr = x64 + (size_t)r * 64;
    float a0 = 0, a1 = 0, a2 = 0;
    #pragma unroll 8
    for (int k = 0; k < 64; ++k) {
        float xv = bf2f(xr[k]);
        a0 = fmaf(xv, w[k * 3 + 0], a0);
        a1 = fmaf(xv, w[k * 3 + 1], a1);
        a2 = fmaf(xv, w[k * 3 + 2], a2);
    }
    float* o = h3 + (size_t)r * 3;
    o[0] = a0; o[1] = a1; o[2] = a2;
}

// final aggregation: h3 vertex-major [i*8+b][3] -> out [b][i][3]
__global__ __launch_bounds__(256) void k_agg3(const float* __restrict__ h3, float* __restrict__ out,
                                              const int* __restrict__ rp, const int* __restrict__ ci,
                                              const float* __restrict__ val, const float* __restrict__ b6) {
    int idx = blockIdx.x * 256 + threadIdx.x;
    if (idx >= MROWS) return;
    int b = idx / NV, i = idx - b * NV;
    float a0 = b6[0], a1 = b6[1], a2 = b6[2];
    int r0 = rp[i], r1 = rp[i + 1];
    for (int e = r0; e < r1; ++e) {
        int j = ci[e];
        float wv = val[e];
        const float* hr = h3 + ((size_t)j * BB + b) * 3;
        a0 = fmaf(wv, hr[0], a0);
        a1 = fmaf(wv, hr[1], a1);
        a2 = fmaf(wv, hr[2], a2);
    }
    float* o = out + (size_t)idx * 3;
    o[0] = a0; o[1] = a1; o[2] = a2;
}

// ---------------- launcher ----------------
extern "C" void kernel_launch(void* const* d_in, const int* in_sizes, int n_in,
                              void* d_out, int out_size, void* d_ws, size_t ws_size,
                              hipStream_t stream) {
    const float* verts = (const float*)d_in[0];
    const float* img   = (const float*)d_in[1];
    const int*   ei    = (const int*)d_in[2];
    const float* W1 = (const float*)d_in[3];  const float* b1 = (const float*)d_in[4];
    const float* W2 = (const float*)d_in[5];  const float* b2 = (const float*)d_in[6];
    const float* W3 = (const float*)d_in[7];  const float* b3 = (const float*)d_in[8];
    const float* W4 = (const float*)d_in[9];  const float* b4 = (const float*)d_in[10];
    const float* W5 = (const float*)d_in[11]; const float* b5 = (const float*)d_in[12];
    const float* W6 = (const float*)d_in[13]; const float* b6 = (const float*)d_in[14];
    float* out = (float*)d_out;

    char* ws = (char*)d_ws;
    size_t off = 0;
    auto carve = [&](size_t bytes) -> void* {
        void* q = ws + off;
        off += (bytes + 255) & ~(size_t)255;
        return q;
    };
    ushort* bufA = (ushort*)carve((size_t)MROWS * 512 * 2);   // r2 / z / h5...
    ushort* bufB = (ushort*)carve((size_t)MROWS * 512 * 2);   // y3 / r4 / x5
    ushort* Wt4  = (ushort*)carve((size_t)512 * 512 * 2);     // W4 transposed bf16
    ushort* W3c  = (ushort*)carve((size_t)512 * 512 * 2);     // W3 cast bf16 (row-major)
    ushort* Wt34 = (ushort*)carve((size_t)512 * 512 * 2);     // (W3W4)^T bf16
    ushort* Wt5  = (ushort*)carve((size_t)64 * 512 * 2);
    float*  basev = (float*)carve((size_t)BB * 512 * 4);
    float*  bw2   = (float*)carve((size_t)BB * 512 * 4);
    float*  CW12  = (float*)carve((size_t)3 * 512 * 4);
    float*  b1w2  = (float*)carve((size_t)512 * 4);
    float*  b3w4  = (float*)carve((size_t)512 * 4);
    int*    deg  = (int*)carve((size_t)NV * 4);
    int*    fill = (int*)carve((size_t)NV * 4);
    float*  dinv = (float*)carve((size_t)NV * 4);
    float*  sV   = (float*)carve((size_t)NV * 4);
    float*  s2V  = (float*)carve((size_t)NV * 4);
    int*    rp   = (int*)carve((size_t)(NV + 1) * 4);
    int*    ci   = (int*)carve((size_t)(NE + NV) * 4);
    float*  valv = (float*)carve((size_t)(NE + NV) * 4);
    float*  aggV  = (float*)carve((size_t)MROWS * 3 * 4);
    float*  aggV2 = (float*)carve((size_t)MROWS * 3 * 4);
    float*  h3   = (float*)carve((size_t)MROWS * 3 * 4);

    dim3 b256(256);
    const int gNV = (NV + 255) / 256;
    const int gMR = (MROWS + 255) / 256;
    // CSR build
    k_init<<<dim3(gNV), b256, 0, stream>>>(deg, fill);
    k_count<<<dim3((NE + 255) / 256), b256, 0, stream>>>(ei, deg);
    k_dinv<<<dim3(gNV), b256, 0, stream>>>(deg, dinv);
    k_scan<<<dim3(1), dim3(1024), 0, stream>>>(deg, rp);
    k_fill<<<dim3((NE + NV + 255) / 256), b256, 0, stream>>>(ei, rp, fill, dinv, ci, valv);
    // scalar chains s = A*1, s2 = A*s
    k_srow<<<dim3(gNV), b256, 0, stream>>>(rp, valv, sV);
    k_s2<<<dim3(gNV), b256, 0, stream>>>(rp, ci, valv, sV, s2V);
    // 3-wide aggs: aggV = A*verts, aggV2 = A*aggV
    k_aggsm<<<dim3(gMR), b256, 0, stream>>>(verts, aggV, rp, ci, valv);
    k_aggsm<<<dim3(gMR), b256, 0, stream>>>(aggV, aggV2, rp, ci, valv);
    // small dense precomputes
    k_l1base<<<dim3(4, BB), dim3(128), 0, stream>>>(img, W1, basev);
    k_matvecs<<<dim3(4, 3), dim3(128), 0, stream>>>(W1, W2, CW12);    // W1v (first 3 rows) * W2
    k_matvecs<<<dim3(4, BB), dim3(128), 0, stream>>>(basev, W2, bw2); // base * W2
    k_matvecs<<<dim3(4, 1), dim3(128), 0, stream>>>(b1, W2, b1w2);    // b1 * W2
    k_matvecs<<<dim3(4, 1), dim3(128), 0, stream>>>(b3, W4, b3w4);    // b3 * W4
    // weight conversions + composite W3*W4 (as Bt format: Wt34[n][k] = (W3W4)[k][n])
    k_wconv<<<dim3((512 * 512 + 255) / 256), b256, 0, stream>>>(W4, Wt4, 512, 512);
    k_wcast<<<dim3((512 * 512 + 255) / 256), b256, 0, stream>>>(W3, W3c, 512 * 512);
    k_wconv<<<dim3((512 * 64 + 255) / 256), b256, 0, stream>>>(W5, Wt5, 512, 64);
    k_gemm<0><<<dim3(32), b256, 0, stream>>>(Wt4, W3c, Wt34, 512, 512, nullptr, nullptr, nullptr);
    // x2 reconstruction (+relu) -> bufA
    k_x2<<<dim3((MROWS + 1) / 2), b256, 0, stream>>>(aggV2, sV, s2V, CW12, bw2, b1w2, b2, bufA);
    // y3 = A*r2 -> bufB ; z = A*y3 -> bufA
    k_aggv<512, 512, false, false><<<dim3(NV), dim3(512), 0, stream>>>(bufA, bufB, rp, ci, valv, nullptr);
    k_aggv<512, 512, false, false><<<dim3(NV), dim3(512), 0, stream>>>(bufB, bufA, rp, ci, valv, nullptr);
    // r4 = relu(z*CW34 + s*b3w4 + b4) -> bufB
    const int nrc = (MROWS + 127) / 128;            // 641
    const int g512 = 8 * ((nrc + 7) / 8) * 4;       // 2592
    const int g64  = 8 * ((nrc + 7) / 8) * 1;       // 648
    k_gemm<1><<<dim3(g512), b256, 0, stream>>>(bufA, Wt34, bufB, MROWS, 512, sV, b3w4, b4);
    // layer 5: h5 = r4*W5 -> bufA ; x5 = A*h5 + b5 -> bufB
    k_gemm<0><<<dim3(g64), b256, 0, stream>>>(bufB, Wt5, bufA, MROWS, 64, nullptr, nullptr, nullptr);
    k_aggv<64, 64, true, false><<<dim3(NV), dim3(64), 0, stream>>>(bufA, bufB, rp, ci, valv, b5);
    // layer 6
    k_l6<<<dim3(gMR), b256, 0, stream>>>(bufB, W6, h3);
    k_agg3<<<dim3(gMR), b256, 0, stream>>>(h3, out, rp, ci, valv, b6);
}